// Round 1
// baseline (146.357 us; speedup 1.0000x reference)
//
#include <hip/hip_runtime.h>

#define BOND   64
#define SITES  256
#define HALF   128
#define NBATCH 128
#define OUTD   10

// d_ws float layout:
//   P0 : [0 .. 1048576)        left-packed  [128 steps][32 g][64 j] float4
//   P1 : [1048576 .. 2097152)  right-packed (transposed, step k = site 255-k)
//   vecs: [2097152 .. 2113536) [2][128][64] propagated end vectors
#define P1_OFF   1048576
#define VEC_OFF  2097152
#define SITE_F4  2048          // float4s per packed site (64*64*2 floats)
#define LPITCH   132           // LDS transpose pitch (floats), 16B-aligned rows

// ---------------------------------------------------------------------------
// Pack kernel: one block per site, LDS transpose so BOTH global reads and
// writes are fully coalesced.  (unchanged from previous version)
// ---------------------------------------------------------------------------
__global__ void __launch_bounds__(256)
mps_pack_kernel(const float* __restrict__ cores, float* __restrict__ P) {
  __shared__ __align__(16) float ld[64 * LPITCH];
  const int s = (int)blockIdx.x;
  const int t = (int)threadIdx.x;
  const float4* src = (const float4*)(cores + (size_t)s * 8192);
  #pragma unroll
  for (int k = 0; k < 8; ++k) {
    const int m = t + 256 * k;              // float4 index in [0,2048)
    const int row = m >> 5;                 // l
    const int c4  = m & 31;                 // float4 within row
    *(float4*)&ld[row * LPITCH + c4 * 4] = src[m];
  }
  __syncthreads();
  const bool right = s >= HALF;
  const int step = right ? (SITES - 1 - s) : s;
  float4* out = (float4*)(P + (right ? P1_OFF : 0)) + (size_t)step * SITE_F4;
  #pragma unroll
  for (int k = 0; k < 8; ++k) {
    const int m = t + 256 * k;              // out float4 index = g*64 + j
    const int g = m >> 6;
    const int j = m & 63;
    float4 v;
    if (!right) {
      const float2 a  = *(const float2*)&ld[(2 * g) * LPITCH + 2 * j];
      const float2 b2 = *(const float2*)&ld[(2 * g + 1) * LPITCH + 2 * j];
      v = make_float4(a.x, a.y, b2.x, b2.y);
    } else {
      v = *(const float4*)&ld[j * LPITCH + 4 * g];
    }
    out[m] = v;
  }
}

// lane -> SGPR broadcast (v_readlane_b32); index is wave-uniform.
__device__ __forceinline__ float rlanef(float v, int l) {
  return __int_as_float(__builtin_amdgcn_readlane(__float_as_int(v), l));
}

// ---------------------------------------------------------------------------
// Chain kernel: 128 blocks x 256 threads (4 waves). Block = (side, batch pair).
// Split-K: wave w owns l-range [16w, 16w+16).
// New step template vs previous version:
//   * raw s_barrier with lgkmcnt-only wait -> the 8-load matrix prefetch stays
//     in flight ACROSS the barrier (old __syncthreads drained vmcnt(0) every
//     step, killing the double buffer: VGPR_Count=36 proved it).
//   * v-window redistribution via v_readlane (SGPR broadcast) instead of the
//     vshw LDS write+read round trip -> ONE LDS round trip per step.
//   * partial reduce as b32 arrays (2 lanes/bank = conflict-free) instead of
//     b128 at 16B stride (8-way conflict).
//   * x staged pre-reversed for side 1.
// ---------------------------------------------------------------------------
__global__ void __launch_bounds__(256, 1)
mps_chain_kernel(const float* __restrict__ input,   // [128][256][2]
                 const float* __restrict__ P,       // packed cores (in ws)
                 const float* __restrict__ lvec,
                 const float* __restrict__ rvec,
                 float* __restrict__ vout) {        // ws + VEC_OFF
  __shared__ __align__(16) float pa0[2][4][BOND];   // [parity][wave][lane] batch0
  __shared__ __align__(16) float pa1[2][4][BOND];   // [parity][wave][lane] batch1
  __shared__ __align__(16) float xsh[2][HALF][2];   // [batch][step][feat] pre-reversed

  const int t    = (int)threadIdx.x;
  const int w    = t >> 6;
  const int lane = t & 63;
  const int side = (int)blockIdx.x & 1;    // pins each side to its own XCD set
  const int pair = (int)blockIdx.x >> 1;
  const int b0   = 2 * pair;
  const int b1   = 2 * pair + 1;

  // stage x: 256 threads, 256 float2 elems (2 batches x 128 steps), reversed
  // for side 1 so the step loop indexes forward for both sides.
  {
    const int bi = t >> 7;                 // batch slot 0/1
    const int st = t & 127;                // step
    const int b  = bi ? b1 : b0;
    const int hs = side ? (HALF - 1 - st) : st;
    const float2 xv =
        *(const float2*)(input + ((size_t)b * SITES + side * HALF + hs) * 2);
    xsh[bi][st][0] = xv.x;
    xsh[bi][st][1] = xv.y;
  }

  const float e = side ? rvec[lane] : lvec[lane];
  float r0 = e, r1 = e;                    // lane j holds v[j] (replicated per wave)

  const int wb = 16 * w;                   // wave's l-window base
  float u0[16], u1[16];                    // SGPR copies of v[wb..wb+16)
  #pragma unroll
  for (int k = 0; k < 16; ++k) {
    u0[k] = rlanef(r0, wb + k);
    u1[k] = rlanef(r1, wb + k);
  }

  // wave w's chunk: g = 8w+jj, float4 {c0[2g][j], c1[2g][j], c0[2g+1][j], c1[2g+1][j]}
  const float4* base = (const float4*)(P + (side ? P1_OFF : 0)) +
                       (size_t)(8 * w) * 64 + lane;

  float4 A[8], B[8];
  #pragma unroll
  for (int j = 0; j < 8; ++j) A[j] = base[j * 64];   // step 0

  __syncthreads();   // xsh visible before first use (one-time full drain: fine)

  #define STEP(CUR, NXT, I)                                                  \
  {                                                                          \
    const int inx = ((I) + 1 < HALF) ? (I) + 1 : (I);                        \
    _Pragma("unroll")                                                        \
    for (int j = 0; j < 8; ++j) NXT[j] = base[(size_t)inx * 2048 + j * 64];  \
    float p00 = 0.f, p01 = 0.f, p10 = 0.f, p11 = 0.f;                        \
    _Pragma("unroll")                                                        \
    for (int g = 0; g < 8; ++g) {                                            \
      const float4 m = CUR[g];                                               \
      p00 = __builtin_fmaf(u0[2 * g], m.x, p00);                             \
      p01 = __builtin_fmaf(u0[2 * g], m.y, p01);                             \
      p10 = __builtin_fmaf(u1[2 * g], m.x, p10);                             \
      p11 = __builtin_fmaf(u1[2 * g], m.y, p11);                             \
      p00 = __builtin_fmaf(u0[2 * g + 1], m.z, p00);                         \
      p01 = __builtin_fmaf(u0[2 * g + 1], m.w, p01);                         \
      p10 = __builtin_fmaf(u1[2 * g + 1], m.z, p10);                         \
      p11 = __builtin_fmaf(u1[2 * g + 1], m.w, p11);                         \
    }                                                                        \
    const float2 x0 = *(const float2*)xsh[0][(I)];                           \
    const float2 x1 = *(const float2*)xsh[1][(I)];                           \
    const float t0 = __builtin_fmaf(x0.x, p00, x0.y * p01);                  \
    const float t1 = __builtin_fmaf(x1.x, p10, x1.y * p11);                  \
    pa0[(I) & 1][w][lane] = t0;                                              \
    pa1[(I) & 1][w][lane] = t1;                                              \
    asm volatile("s_waitcnt lgkmcnt(0)" ::: "memory");                       \
    __builtin_amdgcn_s_barrier();                                            \
    r0 += (pa0[(I) & 1][0][lane] + pa0[(I) & 1][1][lane]) +                  \
          (pa0[(I) & 1][2][lane] + pa0[(I) & 1][3][lane]);                   \
    r1 += (pa1[(I) & 1][0][lane] + pa1[(I) & 1][1][lane]) +                  \
          (pa1[(I) & 1][2][lane] + pa1[(I) & 1][3][lane]);                   \
    _Pragma("unroll")                                                        \
    for (int k = 0; k < 16; ++k) {                                           \
      u0[k] = rlanef(r0, wb + k);                                            \
      u1[k] = rlanef(r1, wb + k);                                            \
    }                                                                        \
  }

  for (int i = 0; i < HALF; i += 2) {
    STEP(A, B, i);
    STEP(B, A, i + 1);
  }
  #undef STEP

  if (w == 0) {
    vout[((size_t)side * NBATCH + b0) * BOND + lane] = r0;
    vout[((size_t)side * NBATCH + b1) * BOND + lane] = r1;
  }
}

// ---------------------------------------------------------------------------
// logits[b][o] = sum_{m,r} vL[b][m] * oc[o][m][r] * vR[b][r]
// ---------------------------------------------------------------------------
__global__ void __launch_bounds__(64)
mps_combine_kernel(const float* __restrict__ oc,    // [10][64][64]
                   const float* __restrict__ vecs,  // ws + VEC_OFF
                   float* __restrict__ out) {       // [128][10]
  __shared__ float vl[BOND];
  const int lane = (int)threadIdx.x;
  const int b = (int)blockIdx.x;
  vl[lane] = vecs[b * BOND + lane];
  const float myvr = vecs[NBATCH * BOND + b * BOND + lane];
  float res[OUTD];
  #pragma unroll
  for (int o = 0; o < OUTD; ++o) {
    float acc = 0.f;
    #pragma unroll
    for (int m = 0; m < BOND; ++m)
      acc = __builtin_fmaf(vl[m], oc[((o * BOND) + m) * BOND + lane], acc);
    acc *= myvr;
    #pragma unroll
    for (int off = 32; off > 0; off >>= 1)
      acc += __shfl_xor(acc, off, 64);
    res[o] = acc;
  }
  if (lane == 0) {
    #pragma unroll
    for (int o = 0; o < OUTD; ++o) out[b * OUTD + o] = res[o];
  }
}

extern "C" void kernel_launch(void* const* d_in, const int* in_sizes, int n_in,
                              void* d_out, int out_size, void* d_ws, size_t ws_size,
                              hipStream_t stream) {
  const float* input = (const float*)d_in[0];   // [128][256][2]
  const float* cores = (const float*)d_in[1];   // [256][64][64][2]
  const float* oc    = (const float*)d_in[2];   // [10][64][64]
  const float* lvec  = (const float*)d_in[3];   // [64]
  const float* rvec  = (const float*)d_in[4];   // [64]
  float* ws  = (float*)d_ws;
  float* out = (float*)d_out;                   // [128][10]

  hipLaunchKernelGGL(mps_pack_kernel, dim3(SITES), dim3(256), 0, stream,
                     cores, ws);
  hipLaunchKernelGGL(mps_chain_kernel, dim3(NBATCH), dim3(256), 0, stream,
                     input, ws, lvec, rvec, ws + VEC_OFF);
  hipLaunchKernelGGL(mps_combine_kernel, dim3(NBATCH), dim3(64), 0, stream,
                     oc, ws + VEC_OFF, out);
}